// Round 1
// 82.841 us; speedup vs baseline: 1.0792x; 1.0792x over previous
//
#include <hip/hip_runtime.h>
#include <math.h>

// Model: tiny transformer, B=32,S=1024,L=2,E=4,H=2,D=2,FFN=16,V=8.
// Collapse: non-causal attention + V=8 vocab => x[b,s] is a pure function of
// (b, tok[b,s]) at every stage (softmax over repeated keys == histogram-
// weighted softmax over the 8 distinct key values). Per batch: histogram[8]
// -> transformer on 8 virtual tokens -> 8x8 logits table -> scatter.
//
// This revision attacks the latency chain of the ~9us kernel tail:
//  (a) all 520 weight floats staged to LDS in 2 parallel rounds, overlapped
//      with the token loads (was: scalar loads inside the serial chain),
//  (b) histogram via per-wave ballot/popc (was: 1024 same-address LDS atomics),
//  (c) attention parallel over 16 threads (token x head), FFN parallel over
//      128 threads (token x feature; 1 erff/thread + shfl_xor tree reduce).

#define Bz  32
#define Sz  1024
#define Lz  2
#define Ez  4
#define Hz  2
#define Dz  2
#define FFNz 16
#define Vz  8
#define EPSz 1e-5f

#define CHUNKS 8                 // blocks per batch
#define POSPC (Sz / CHUNKS)      // 128 positions per block
#define NT 256

__device__ __forceinline__ void layernorm4(const float* x, const float* g,
                                           const float* b, float* h) {
    float mu = 0.25f * (x[0] + x[1] + x[2] + x[3]);
    float d0 = x[0] - mu, d1 = x[1] - mu, d2 = x[2] - mu, d3 = x[3] - mu;
    float var = 0.25f * (d0 * d0 + d1 * d1 + d2 * d2 + d3 * d3);
    float r = 1.0f / sqrtf(var + EPSz);
    h[0] = d0 * r * g[0] + b[0];
    h[1] = d1 * r * g[1] + b[1];
    h[2] = d2 * r * g[2] + b[2];
    h[3] = d3 * r * g[3] + b[3];
}

__global__ __launch_bounds__(NT) void tformer_collapse(
    const int* __restrict__ tok,
    const float* __restrict__ emb,
    const float* __restrict__ ln1_g, const float* __restrict__ ln1_b,
    const float* __restrict__ wqkv, const float* __restrict__ wo,
    const float* __restrict__ ln2_g, const float* __restrict__ ln2_b,
    const float* __restrict__ w1, const float* __restrict__ b1,
    const float* __restrict__ w2, const float* __restrict__ b2,
    const float* __restrict__ out_w,
    float* __restrict__ out)
{
    __shared__ int   toks[Sz];
    __shared__ int   hist[Vz];
    // staged weights (520 floats total)
    __shared__ float s_wqkv[Lz * 3 * Ez * Ez];   // 96
    __shared__ float s_w1[Lz * FFNz * Ez];       // 128
    __shared__ float s_emb[Vz * Ez];             // 32
    __shared__ float s_w2[Lz * Ez * FFNz];       // 128
    __shared__ float s_wo[Lz * Ez * Ez];         // 32
    __shared__ float s_outw[Vz * Ez];            // 32
    __shared__ float s_b1[Lz * FFNz];            // 32
    __shared__ float s_b2[Lz * Ez];              // 8
    __shared__ float s_ln1g[Lz * Ez], s_ln1b[Lz * Ez];  // 8+8
    __shared__ float s_ln2g[Lz * Ez], s_ln2b[Lz * Ez];  // 8+8
    // per-virtual-token state
    __shared__ float sx[Vz][Ez];     // residual stream
    __shared__ float sq[Vz][Ez];     // q
    __shared__ float kv_k[Vz][Ez];
    __shared__ float kv_v[Vz][Ez];
    __shared__ float so[Vz][Ez];     // attn output
    __shared__ float sh2[Vz][Ez];    // LN2 output
    __shared__ __align__(16) float table[Vz][Vz];

    const int b     = blockIdx.x / CHUNKS;
    const int chunk = blockIdx.x % CHUNKS;
    const int tid   = threadIdx.x;

    if (tid < Vz) hist[tid] = 0;

    // --- issue token loads early (into regs; consumed after sync1) ---
    const int* tb = tok + b * Sz;
    int tkr[Sz / NT];
    #pragma unroll
    for (int k = 0; k < Sz / NT; ++k) tkr[k] = tb[tid + k * NT];

    // --- parallel weight staging: all 520 floats in 2 load rounds ---
    if (tid < 96)        s_wqkv[tid]      = wqkv[tid];
    else if (tid < 224)  s_w1[tid - 96]   = w1[tid - 96];
    else                 s_emb[tid - 224] = emb[tid - 224];

    if (tid < 128)       s_w2[tid]          = w2[tid];
    else if (tid < 160)  s_wo[tid - 128]    = wo[tid - 128];
    else if (tid < 192)  s_outw[tid - 160]  = out_w[tid - 160];
    else if (tid < 224)  s_b1[tid - 192]    = b1[tid - 192];
    else if (tid < 232)  s_b2[tid - 224]    = b2[tid - 224];
    else if (tid < 240)  s_ln1g[tid - 232]  = ln1_g[tid - 232];
    else if (tid < 248)  s_ln1b[tid - 240]  = ln1_b[tid - 240];
    else                 s_ln2g[tid - 248]  = ln2_g[tid - 248];
    if (tid < 8)         s_ln2b[tid]        = ln2_b[tid];

    __syncthreads();   // sync1: hist zeroed, weights staged

    // --- histogram via per-wave ballot (no same-address atomic storm) ---
    int c[Vz] = {0, 0, 0, 0, 0, 0, 0, 0};
    #pragma unroll
    for (int k = 0; k < Sz / NT; ++k) {
        int t = tkr[k];
        toks[tid + k * NT] = t;
        #pragma unroll
        for (int v = 0; v < Vz; ++v)
            c[v] += (int)__popcll(__ballot(t == v));
    }
    if ((tid & 63) == 0) {       // one leader per wave: 4x8 atomics total
        #pragma unroll
        for (int v = 0; v < Vz; ++v) atomicAdd(&hist[v], c[v]);
    }
    __syncthreads();   // sync2: hist + toks final

    // counts for the 16 attention threads
    float cntr[Vz];
    if (tid < Vz * Hz) {
        #pragma unroll
        for (int j = 0; j < Vz; ++j) cntr[j] = (float)hist[j];
    }
    // init residual stream from embedding
    if (tid < Vz) {
        #pragma unroll
        for (int e = 0; e < Ez; ++e) sx[tid][e] = s_emb[tid * Ez + e];
    }
    // (no sync needed: phase A below reads sx only from its own thread)

    #pragma unroll
    for (int l = 0; l < Lz; ++l) {
        // --- A: LN1 + QKV projection (8 threads) ---
        if (tid < Vz) {
            const int t = tid;
            float h[Ez];
            layernorm4(&sx[t][0], s_ln1g + l * Ez, s_ln1b + l * Ez, h);
            const float* wq = s_wqkv + l * 3 * Ez * Ez;
            #pragma unroll
            for (int f = 0; f < Ez; ++f) {
                float aq = 0.f, ak = 0.f, av = 0.f;
                #pragma unroll
                for (int e = 0; e < Ez; ++e) {
                    aq += wq[f * Ez + e] * h[e];
                    ak += wq[(Ez + f) * Ez + e] * h[e];
                    av += wq[(2 * Ez + f) * Ez + e] * h[e];
                }
                sq[t][f]   = aq;
                kv_k[t][f] = ak;
                kv_v[t][f] = av;
            }
        }
        __syncthreads();

        // --- B: histogram-weighted attention (16 threads: token x head) ---
        if (tid < Vz * Hz) {
            const int t = tid >> 1, hh = tid & 1;
            const float q0 = sq[t][hh * Dz + 0], q1 = sq[t][hh * Dz + 1];
            float sc[Vz];
            float m = -1e30f;
            #pragma unroll
            for (int j = 0; j < Vz; ++j) {
                float s = (q0 * kv_k[j][hh * Dz + 0] +
                           q1 * kv_k[j][hh * Dz + 1]) * 0.70710678118654752f;
                sc[j] = s;
                m = fmaxf(m, s);
            }
            float Z = 0.f, a0 = 0.f, a1 = 0.f;
            #pragma unroll
            for (int j = 0; j < Vz; ++j) {
                float w = cntr[j] * expf(sc[j] - m);
                Z  += w;
                a0 += w * kv_v[j][hh * Dz + 0];
                a1 += w * kv_v[j][hh * Dz + 1];
            }
            so[t][hh * Dz + 0] = a0 / Z;
            so[t][hh * Dz + 1] = a1 / Z;
        }
        __syncthreads();

        // --- C: WO projection + residual + LN2 (8 threads) ---
        if (tid < Vz) {
            const int t = tid;
            float x[Ez], o[Ez];
            #pragma unroll
            for (int e = 0; e < Ez; ++e) { x[e] = sx[t][e]; o[e] = so[t][e]; }
            #pragma unroll
            for (int f = 0; f < Ez; ++f) {
                float s = 0.f;
                #pragma unroll
                for (int e = 0; e < Ez; ++e)
                    s += o[e] * s_wo[(l * Ez + f) * Ez + e];
                x[f] += s;
            }
            #pragma unroll
            for (int e = 0; e < Ez; ++e) sx[t][e] = x[e];
            float h2[Ez];
            layernorm4(x, s_ln2g + l * Ez, s_ln2b + l * Ez, h2);
            #pragma unroll
            for (int e = 0; e < Ez; ++e) sh2[t][e] = h2[e];
        }
        __syncthreads();

        // --- D: FFN (128 threads: token x feature; 1 erff per thread) ---
        if (tid < Vz * FFNz) {
            const int t = tid >> 4, f = tid & 15;
            const float* w1r = s_w1 + (l * FFNz + f) * Ez;
            float u = s_b1[l * FFNz + f]
                    + w1r[0] * sh2[t][0] + w1r[1] * sh2[t][1]
                    + w1r[2] * sh2[t][2] + w1r[3] * sh2[t][3];
            // exact GELU: 0.5*u*(1+erf(u/sqrt(2)))
            float g = 0.5f * u * (1.0f + erff(u * 0.70710678118654752f));
            float r0 = g * s_w2[(l * Ez + 0) * FFNz + f];
            float r1 = g * s_w2[(l * Ez + 1) * FFNz + f];
            float r2 = g * s_w2[(l * Ez + 2) * FFNz + f];
            float r3 = g * s_w2[(l * Ez + 3) * FFNz + f];
            // tree-reduce over the 16 feature lanes (xor masks stay in-group)
            #pragma unroll
            for (int msk = 1; msk < FFNz; msk <<= 1) {
                r0 += __shfl_xor(r0, msk);
                r1 += __shfl_xor(r1, msk);
                r2 += __shfl_xor(r2, msk);
                r3 += __shfl_xor(r3, msk);
            }
            if (f == 0) {
                sx[t][0] += r0 + s_b2[l * Ez + 0];
                sx[t][1] += r1 + s_b2[l * Ez + 1];
                sx[t][2] += r2 + s_b2[l * Ez + 2];
                sx[t][3] += r3 + s_b2[l * Ez + 3];
            }
        }
        __syncthreads();
    }

    // --- logits table (64 threads: token x vocab) ---
    if (tid < Vz * Vz) {
        const int t = tid >> 3, vv = tid & 7;
        const float* ow = s_outw + vv * Ez;
        table[t][vv] = sx[t][0] * ow[0] + sx[t][1] * ow[1]
                     + sx[t][2] * ow[2] + sx[t][3] * ow[3];
    }
    __syncthreads();

    // --- scatter: 128 positions x 8 floats = 256 float4 stores (coalesced) ---
    const int posBase = chunk * POSPC;
    const int p    = tid >> 1;      // 0..127
    const int part = tid & 1;       // which float4 of the 8-float row
    const int tk   = toks[posBase + p];
    float4 val = ((const float4*)&table[tk][0])[part];
    float4* out4 = (float4*)(out + ((size_t)b * Sz + posBase) * Vz);
    out4[tid] = val;
}

extern "C" void kernel_launch(void* const* d_in, const int* in_sizes, int n_in,
                              void* d_out, int out_size, void* d_ws, size_t ws_size,
                              hipStream_t stream) {
    const int*   tok   = (const int*)  d_in[0];
    const float* emb   = (const float*)d_in[1];
    const float* ln1_g = (const float*)d_in[2];
    const float* ln1_b = (const float*)d_in[3];
    const float* wqkv  = (const float*)d_in[4];
    const float* wo    = (const float*)d_in[5];
    const float* ln2_g = (const float*)d_in[6];
    const float* ln2_b = (const float*)d_in[7];
    const float* w1    = (const float*)d_in[8];
    const float* b1    = (const float*)d_in[9];
    const float* w2    = (const float*)d_in[10];
    const float* b2    = (const float*)d_in[11];
    const float* out_w = (const float*)d_in[12];
    float* out = (float*)d_out;

    dim3 grid(Bz * CHUNKS);   // 256 blocks -> one per CU
    dim3 block(NT);
    tformer_collapse<<<grid, block, 0, stream>>>(
        tok, emb, ln1_g, ln1_b, wqkv, wo, ln2_g, ln2_b,
        w1, b1, w2, b2, out_w, out);
}